// Round 1
// baseline (1426.236 us; speedup 1.0000x reference)
//
#include <hip/hip_runtime.h>
#include <math.h>

#define BN   2
#define CIN  96
#define HH   40
#define WW   40
#define LL   1600
#define DIN  192
#define NS   16
#define RR   6
#define KK   4

__device__ __forceinline__ float sigmoidf_(float x){ return 1.0f/(1.0f+expf(-x)); }
__device__ __forceinline__ float softplusf_(float x){ return x > 20.0f ? x : log1pf(expf(x)); }

// cross_scan pixel index for direction k at scan step l (H==W==40)
__device__ __forceinline__ int pix_of(int k, int l){
  int ll = (k >= 2) ? (LL - 1 - l) : l;
  if (k & 1) return (ll % WW) * WW + (ll / WW);
  return ll;
}

// ---------------- K1: in_proj (1x1) for both modalities ----------------
// grid: (L/64, 2*B), block 256. xproj layout [mb][o][p]
__global__ void k_inproj(const float* __restrict__ x_rgb, const float* __restrict__ x_e,
                         const float* __restrict__ w_rgb, const float* __restrict__ w_e,
                         float* __restrict__ xproj){
  __shared__ float xin[CIN][64];
  int l0 = blockIdx.x * 64;
  int mb = blockIdx.y;            // m*BN + b
  int m = mb / BN, b = mb % BN;
  const float* xsrc = (m == 0 ? x_rgb : x_e) + (size_t)b * CIN * LL;
  const float* w    = (m == 0 ? w_rgb : w_e);
  for (int idx = threadIdx.x; idx < CIN * 64; idx += blockDim.x){
    int c = idx >> 6, ll = idx & 63;
    xin[c][ll] = xsrc[c * LL + l0 + ll];
  }
  __syncthreads();
  for (int oidx = threadIdx.x; oidx < DIN * 64; oidx += blockDim.x){
    int o = oidx >> 6, ll = oidx & 63;
    const float* wr = w + o * CIN;
    float acc = 0.f;
    #pragma unroll 8
    for (int c = 0; c < CIN; ++c) acc += wr[c] * xin[c][ll];
    xproj[((size_t)mb * DIN + o) * LL + l0 + ll] = acc;
  }
}

// ---------------- K2: depthwise 3x3 + bias + SiLU, + mean for SE --------
// grid: (DIN, 2*B), block 256
__global__ void k_conv(const float* __restrict__ xproj, const float* __restrict__ conv_w,
                       const float* __restrict__ conv_b, float* __restrict__ x_act,
                       float* __restrict__ sq){
  __shared__ float pl[LL];
  __shared__ float red[4];
  int d  = blockIdx.x;
  int mb = blockIdx.y;
  const float* src = xproj + ((size_t)mb * DIN + d) * LL;
  for (int p = threadIdx.x; p < LL; p += blockDim.x) pl[p] = src[p];
  __syncthreads();
  float cw[9];
  #pragma unroll
  for (int j = 0; j < 9; ++j) cw[j] = conv_w[d * 9 + j];
  float bias = conv_b[d];
  float* dst = x_act + ((size_t)mb * DIN + d) * LL;
  float lsum = 0.f;
  for (int p = threadIdx.x; p < LL; p += blockDim.x){
    int py = p / WW, px = p % WW;
    float acc = bias;
    #pragma unroll
    for (int dy = -1; dy <= 1; ++dy){
      int yy = py + dy;
      if (yy < 0 || yy >= HH) continue;
      #pragma unroll
      for (int dx = -1; dx <= 1; ++dx){
        int xx = px + dx;
        if (xx < 0 || xx >= WW) continue;
        acc += cw[(dy + 1) * 3 + (dx + 1)] * pl[yy * WW + xx];
      }
    }
    float s = acc * sigmoidf_(acc);
    dst[p] = s;
    lsum += s;
  }
  #pragma unroll
  for (int off = 32; off; off >>= 1) lsum += __shfl_down(lsum, off);
  if ((threadIdx.x & 63) == 0) red[threadIdx.x >> 6] = lsum;
  __syncthreads();
  if (threadIdx.x == 0)
    sq[mb * DIN + d] = (red[0] + red[1] + red[2] + red[3]) * (1.0f / LL);
}

// ---------------- K3: cross squeeze-excitation ----------------
// grid: 2*B blocks of 192 threads. exc[mb][d]
__global__ void k_se(const float* __restrict__ sq,
                     const float* __restrict__ fc1_w1, const float* __restrict__ fc1_w2,
                     const float* __restrict__ fc2_w1, const float* __restrict__ fc2_w2,
                     float* __restrict__ exc){
  __shared__ float s[DIN];
  __shared__ float hid[12];
  int mb = blockIdx.x; int m = mb / BN;
  const float* w1 = (m == 0 ? fc1_w1 : fc2_w1);
  const float* w2 = (m == 0 ? fc1_w2 : fc2_w2);
  int t = threadIdx.x;
  s[t] = sq[mb * DIN + t];
  __syncthreads();
  if (t < 12){
    float a = 0.f;
    for (int c = 0; c < DIN; ++c) a += w1[t * DIN + c] * s[c];
    hid[t] = a * sigmoidf_(a);
  }
  __syncthreads();
  float e = 0.f;
  #pragma unroll
  for (int j = 0; j < 12; ++j) e += w2[t * 12 + j] * hid[j];
  exc[mb * DIN + t] = sigmoidf_(e);
}

// ---------------- K4: x_proj -> t rows (dt 0..5, B 6..21, C 22..37) -----
// grid: (L/64, K, 2*B), block 256. t layout [mb][k][c][l]
__global__ void k_xproj(const float* __restrict__ x_act,
                        const float* __restrict__ xp1, const float* __restrict__ xp2,
                        float* __restrict__ t_ws){
  __shared__ float xs_t[DIN][64];
  int l0 = blockIdx.x * 64;
  int k  = blockIdx.y;
  int mb = blockIdx.z; int m = mb / BN;
  const float* xw = (m == 0 ? xp1 : xp2) + k * 38 * DIN;
  const float* xa = x_act + (size_t)mb * DIN * LL;
  for (int idx = threadIdx.x; idx < DIN * 64; idx += blockDim.x){
    int d = idx >> 6, ll = idx & 63;
    xs_t[d][ll] = xa[d * LL + pix_of(k, l0 + ll)];
  }
  __syncthreads();
  float* tout = t_ws + ((size_t)mb * KK + k) * 38 * LL;
  for (int oidx = threadIdx.x; oidx < 38 * 64; oidx += blockDim.x){
    int c = oidx >> 6, ll = oidx & 63;
    const float* wr = xw + c * DIN;
    float acc = 0.f;
    #pragma unroll 8
    for (int d = 0; d < DIN; ++d) acc += wr[d] * xs_t[d][ll];
    tout[c * LL + l0 + ll] = acc;
  }
}

// ---------------- K5: selective scan (cross C/D), 16 lanes per chain ----
// grid: 768 blocks of 64 threads. y_scan layout [mb][k][l][d] (d fastest)
__global__ void __launch_bounds__(64) k_scan(
    const float* __restrict__ x_act, const float* __restrict__ t_ws,
    const float* __restrict__ Alog1, const float* __restrict__ Alog2,
    const float* __restrict__ D1,    const float* __restrict__ D2,
    const float* __restrict__ dtw1,  const float* __restrict__ dtb1,
    const float* __restrict__ dtw2,  const float* __restrict__ dtb2,
    float* __restrict__ y_scan){
  int chain = blockIdx.x * 4 + (threadIdx.x >> 4);   // m,b,k,d order
  int n = threadIdx.x & 15;
  int d   = chain % DIN;
  int tmp = chain / DIN;
  int k   = tmp % KK;
  int mb  = tmp / KK;
  int m = mb / BN, b = mb % BN;
  int kd = k * DIN + d;

  const float* Alog = (m == 0 ? Alog1 : Alog2);
  float An = -expf(Alog[kd * NS + n]);
  float Dv = (m == 0 ? D2 : D1)[kd];
  const float* dtw = (m == 0 ? dtw1 : dtw2) + kd * RR;
  float w0 = dtw[0], w1 = dtw[1], w2 = dtw[2], w3 = dtw[3], w4 = dtw[4], w5 = dtw[5];
  float dbias = (m == 0 ? dtb1 : dtb2)[kd];

  const float* tm = t_ws + ((size_t)mb * KK + k) * 38 * LL;        // own modality
  const float* tB = tm + (6 + n) * LL;
  const float* tC = t_ws + (((size_t)(1 - m) * BN + b) * KK + k) * 38 * LL + (22 + n) * LL; // other modality C
  const float* up = x_act + ((size_t)mb * DIN + d) * LL;
  float* yout = y_scan + ((size_t)mb * KK + k) * LL * DIN + d;

  float h = 0.f;
  for (int l = 0; l < LL; ++l){
    float dtpre = w0 * tm[l] + w1 * tm[LL + l] + w2 * tm[2 * LL + l]
                + w3 * tm[3 * LL + l] + w4 * tm[4 * LL + l] + w5 * tm[5 * LL + l] + dbias;
    float dsp = softplusf_(dtpre);
    float u  = up[pix_of(k, l)];
    float Bv = tB[l];
    float Cv = tC[l];
    float dA = expf(dsp * An);
    h = dA * h + dsp * Bv * u;
    float yv = h * Cv;
    yv += __shfl_xor(yv, 8, 16);
    yv += __shfl_xor(yv, 4, 16);
    yv += __shfl_xor(yv, 2, 16);
    yv += __shfl_xor(yv, 1, 16);
    if (n == 0) yout[(size_t)l * DIN] = yv + Dv * u;
  }
}

// ---------------- K6: cross_merge + LayerNorm2d + cross SE scale --------
// grid: (L, 2*B), block 192. y_final layout [mb][p][d]
__global__ void k_merge(const float* __restrict__ y_scan, const float* __restrict__ exc,
                        const float* __restrict__ n1g, const float* __restrict__ n1b,
                        const float* __restrict__ n2g, const float* __restrict__ n2b,
                        float* __restrict__ y_final){
  __shared__ float red[8];
  int p  = blockIdx.x;
  int mb = blockIdx.y;
  int m = mb / BN, b = mb % BN;
  int d = threadIdx.x;
  int lt = (p % WW) * WW + (p / WW);
  const float* yb = y_scan + (size_t)mb * KK * LL * DIN;
  float v = yb[((size_t)0 * LL + p) * DIN + d]
          + yb[((size_t)2 * LL + (LL - 1 - p)) * DIN + d]
          + yb[((size_t)1 * LL + lt) * DIN + d]
          + yb[((size_t)3 * LL + (LL - 1 - lt)) * DIN + d];
  float s = v, s2 = v * v;
  #pragma unroll
  for (int off = 32; off; off >>= 1){
    s  += __shfl_down(s, off);
    s2 += __shfl_down(s2, off);
  }
  int wv = threadIdx.x >> 6;
  if ((threadIdx.x & 63) == 0){ red[wv] = s; red[4 + wv] = s2; }
  __syncthreads();
  float S  = red[0] + red[1] + red[2];
  float S2 = red[4] + red[5] + red[6];
  float mu  = S * (1.0f / DIN);
  float var = S2 * (1.0f / DIN) - mu * mu;
  float inv = rsqrtf(var + 1e-5f);
  const float* g  = (m == 0 ? n1g : n2g);
  const float* bb = (m == 0 ? n1b : n2b);
  float yv = (v - mu) * inv * g[d] + bb[d];
  yv *= exc[((1 - m) * BN + b) * DIN + d];     // cross SE: y_r * exc_e, y_e * exc_r
  y_final[((size_t)mb * LL + p) * DIN + d] = yv;
}

// ---------------- K7: out_proj (96 x 384) ----------------
// grid: (L/32, B), block 256. LDS tile padded to stride 385 (conflict-free)
__global__ void k_out(const float* __restrict__ y_final, const float* __restrict__ wout,
                      float* __restrict__ out){
  __shared__ float yt[32 * 385];
  int p0 = blockIdx.x * 32;
  int b  = blockIdx.y;
  for (int idx = threadIdx.x; idx < 32 * 384; idx += blockDim.x){
    int pp = idx / 384, c = idx % 384;
    int m = c / DIN, d = c % DIN;
    yt[pp * 385 + c] = y_final[(((size_t)(m * BN + b)) * LL + p0 + pp) * DIN + d];
  }
  __syncthreads();
  int pp = threadIdx.x & 31;
  int og = threadIdx.x >> 5;     // 0..7
  #pragma unroll
  for (int i = 0; i < 12; ++i){
    int o = og * 12 + i;
    const float* wr = wout + o * 2 * DIN;
    float acc = 0.f;
    #pragma unroll 8
    for (int c = 0; c < 2 * DIN; ++c) acc += wr[c] * yt[pp * 385 + c];
    out[((size_t)b * CIN + o) * LL + p0 + pp] = acc;
  }
}

extern "C" void kernel_launch(void* const* d_in, const int* in_sizes, int n_in,
                              void* d_out, int out_size, void* d_ws, size_t ws_size,
                              hipStream_t stream){
  const float* x_rgb   = (const float*)d_in[0];
  const float* x_e     = (const float*)d_in[1];
  const float* in_w    = (const float*)d_in[2];
  const float* in_mx_w = (const float*)d_in[3];
  const float* conv_w  = (const float*)d_in[4];
  const float* conv_b  = (const float*)d_in[5];
  const float* xp1     = (const float*)d_in[6];
  const float* xp2     = (const float*)d_in[7];
  const float* dtw1    = (const float*)d_in[8];
  const float* dtb1    = (const float*)d_in[9];
  const float* dtw2    = (const float*)d_in[10];
  const float* dtb2    = (const float*)d_in[11];
  const float* Alog1   = (const float*)d_in[12];
  const float* Alog2   = (const float*)d_in[13];
  const float* D1      = (const float*)d_in[14];
  const float* D2      = (const float*)d_in[15];
  const float* n1g     = (const float*)d_in[16];
  const float* n1b     = (const float*)d_in[17];
  const float* n2g     = (const float*)d_in[18];
  const float* n2b     = (const float*)d_in[19];
  const float* fc1_w1  = (const float*)d_in[20];
  const float* fc1_w2  = (const float*)d_in[21];
  const float* fc2_w1  = (const float*)d_in[22];
  const float* fc2_w2  = (const float*)d_in[23];
  const float* wout    = (const float*)d_in[24];

  float* ws = (float*)d_ws;
  // region plan (floats):
  //   [0,            1228800) : x_act  (conv+silu output)        4.9 MB
  //   [1228800,      2457600) : xproj (K1 out; reused as y_final) 4.9 MB
  //   [2457600,      3430400) : t     (dt/B/C rows)               3.9 MB
  //   [3430400,     13260800) : y_scan [mb][k][l][d]             39.3 MB
  //   [13260800,    13261568) : sq
  //   [13261568,    13262336) : exc                     total ~50.6 MB
  float* x_act   = ws;
  float* xproj   = ws + 1228800;
  float* y_final = xproj;             // xproj dead after k_conv
  float* t_ws    = ws + 2457600;
  float* y_scan  = ws + 3430400;
  float* sq      = ws + 13260800;
  float* exc     = ws + 13261568;

  k_inproj<<<dim3(LL / 64, 2 * BN), 256, 0, stream>>>(x_rgb, x_e, in_w, in_mx_w, xproj);
  k_conv  <<<dim3(DIN, 2 * BN), 256, 0, stream>>>(xproj, conv_w, conv_b, x_act, sq);
  k_se    <<<2 * BN, DIN, 0, stream>>>(sq, fc1_w1, fc1_w2, fc2_w1, fc2_w2, exc);
  k_xproj <<<dim3(LL / 64, KK, 2 * BN), 256, 0, stream>>>(x_act, xp1, xp2, t_ws);
  k_scan  <<<768, 64, 0, stream>>>(x_act, t_ws, Alog1, Alog2, D1, D2,
                                   dtw1, dtb1, dtw2, dtb2, y_scan);
  k_merge <<<dim3(LL, 2 * BN), DIN, 0, stream>>>(y_scan, exc, n1g, n1b, n2g, n2b, y_final);
  k_out   <<<dim3(LL / 32, BN), 256, 0, stream>>>(y_final, wout, (float*)d_out);
}

// Round 2
// 417.860 us; speedup vs baseline: 3.4132x; 3.4132x over previous
//
#include <hip/hip_runtime.h>
#include <math.h>

#define BN   2
#define CIN  96
#define HH   40
#define WW   40
#define LL   1600
#define DIN  192
#define NS   16
#define RR   6
#define KK   4

__device__ __forceinline__ float sigmoidf_(float x){ return 1.0f/(1.0f+expf(-x)); }
__device__ __forceinline__ float softplusf_(float x){ return x > 20.0f ? x : log1pf(expf(x)); }

// ---------------- K1: in_proj (1x1) for both modalities ----------------
// grid: (L/64, 2*B), block 256. xproj layout [mb][o][p]
__global__ void k_inproj(const float* __restrict__ x_rgb, const float* __restrict__ x_e,
                         const float* __restrict__ w_rgb, const float* __restrict__ w_e,
                         float* __restrict__ xproj){
  __shared__ float xin[CIN][64];
  int l0 = blockIdx.x * 64;
  int mb = blockIdx.y;            // m*BN + b
  int m = mb / BN, b = mb % BN;
  const float* xsrc = (m == 0 ? x_rgb : x_e) + (size_t)b * CIN * LL;
  const float* w    = (m == 0 ? w_rgb : w_e);
  for (int idx = threadIdx.x; idx < CIN * 64; idx += blockDim.x){
    int c = idx >> 6, ll = idx & 63;
    xin[c][ll] = xsrc[c * LL + l0 + ll];
  }
  __syncthreads();
  for (int oidx = threadIdx.x; oidx < DIN * 64; oidx += blockDim.x){
    int o = oidx >> 6, ll = oidx & 63;
    const float* wr = w + o * CIN;
    float acc = 0.f;
    #pragma unroll 8
    for (int c = 0; c < CIN; ++c) acc += wr[c] * xin[c][ll];
    xproj[((size_t)mb * DIN + o) * LL + l0 + ll] = acc;
  }
}

// ---------------- K2: depthwise 3x3 + bias + SiLU, transpose, SE mean ---
// grid: (DIN, 2*B), block 256
__global__ void k_conv(const float* __restrict__ xproj, const float* __restrict__ conv_w,
                       const float* __restrict__ conv_b, float* __restrict__ x_act,
                       float* __restrict__ x_actT, float* __restrict__ sq){
  __shared__ float pl[LL];
  __shared__ float sact[LL + HH];    // padded: index l + l/40
  __shared__ float red[4];
  int d  = blockIdx.x;
  int mb = blockIdx.y;
  const float* src = xproj + ((size_t)mb * DIN + d) * LL;
  for (int p = threadIdx.x; p < LL; p += blockDim.x) pl[p] = src[p];
  __syncthreads();
  float cw[9];
  #pragma unroll
  for (int j = 0; j < 9; ++j) cw[j] = conv_w[d * 9 + j];
  float bias = conv_b[d];
  float* dst = x_act + ((size_t)mb * DIN + d) * LL;
  float lsum = 0.f;
  for (int p = threadIdx.x; p < LL; p += blockDim.x){
    int py = p / WW, px = p % WW;
    float acc = bias;
    #pragma unroll
    for (int dy = -1; dy <= 1; ++dy){
      int yy = py + dy;
      if (yy < 0 || yy >= HH) continue;
      #pragma unroll
      for (int dx = -1; dx <= 1; ++dx){
        int xx = px + dx;
        if (xx < 0 || xx >= WW) continue;
        acc += cw[(dy + 1) * 3 + (dx + 1)] * pl[yy * WW + xx];
      }
    }
    float s = acc * sigmoidf_(acc);
    dst[p] = s;
    sact[p + p / WW] = s;
    lsum += s;
  }
  #pragma unroll
  for (int off = 32; off; off >>= 1) lsum += __shfl_down(lsum, off);
  if ((threadIdx.x & 63) == 0) red[threadIdx.x >> 6] = lsum;
  __syncthreads();
  if (threadIdx.x == 0)
    sq[mb * DIN + d] = (red[0] + red[1] + red[2] + red[3]) * (1.0f / LL);
  // transposed plane: x_actT[q] = x_act at pixel (q%40)*40 + q/40
  float* dstT = x_actT + ((size_t)mb * DIN + d) * LL;
  for (int q = threadIdx.x; q < LL; q += blockDim.x){
    int l = (q % WW) * WW + q / WW;
    dstT[q] = sact[l + l / WW];
  }
}

// ---------------- K3: cross squeeze-excitation ----------------
// grid: 2*B blocks of 192 threads. exc[mb][d]
__global__ void k_se(const float* __restrict__ sq,
                     const float* __restrict__ fc1_w1, const float* __restrict__ fc1_w2,
                     const float* __restrict__ fc2_w1, const float* __restrict__ fc2_w2,
                     float* __restrict__ exc){
  __shared__ float s[DIN];
  __shared__ float hid[12];
  int mb = blockIdx.x; int m = mb / BN;
  const float* w1 = (m == 0 ? fc1_w1 : fc2_w1);
  const float* w2 = (m == 0 ? fc1_w2 : fc2_w2);
  int t = threadIdx.x;
  s[t] = sq[mb * DIN + t];
  __syncthreads();
  if (t < 12){
    float a = 0.f;
    for (int c = 0; c < DIN; ++c) a += w1[t * DIN + c] * s[c];
    hid[t] = a * sigmoidf_(a);
  }
  __syncthreads();
  float e = 0.f;
  #pragma unroll
  for (int j = 0; j < 12; ++j) e += w2[t * 12 + j] * hid[j];
  exc[mb * DIN + t] = sigmoidf_(e);
}

// ---------------- K4: x_proj -> tdt rows, Bt/Ct in [l][n] layout --------
// grid: (L/64, K, 2*B), block 256
__global__ void k_xproj(const float* __restrict__ x_act, const float* __restrict__ x_actT,
                        const float* __restrict__ xp1, const float* __restrict__ xp2,
                        float* __restrict__ tdt, float* __restrict__ Bt,
                        float* __restrict__ Ct){
  __shared__ float xs_t[DIN][64];
  int l0 = blockIdx.x * 64;
  int k  = blockIdx.y;
  int mb = blockIdx.z; int m = mb / BN;
  const float* xw = (m == 0 ? xp1 : xp2) + k * 38 * DIN;
  const float* xa = ((k & 1) ? x_actT : x_act) + (size_t)mb * DIN * LL;
  bool rev = (k >= 2);
  for (int idx = threadIdx.x; idx < DIN * 64; idx += blockDim.x){
    int dd = idx >> 6, ll = idx & 63;
    int l = l0 + ll; if (rev) l = LL - 1 - l;
    xs_t[dd][ll] = xa[dd * LL + l];
  }
  __syncthreads();
  int mbk = mb * KK + k;
  for (int oidx = threadIdx.x; oidx < 38 * 64; oidx += blockDim.x){
    int c = oidx >> 6, ll = oidx & 63;
    const float* wr = xw + c * DIN;
    float acc = 0.f;
    #pragma unroll 8
    for (int dd = 0; dd < DIN; ++dd) acc += wr[dd] * xs_t[dd][ll];
    int l = l0 + ll;
    if (c < RR)            tdt[((size_t)mbk * RR + c) * LL + l] = acc;
    else if (c < RR + NS)  Bt[((size_t)mbk * LL + l) * NS + (c - RR)] = acc;
    else                   Ct[((size_t)mbk * LL + l) * NS + (c - RR - NS)] = acc;
  }
}

// ---------------- K5: dt projection + softplus -> dsp[mbk][d][l] --------
// grid: (L/64, 16), block 256
__global__ void k_dt(const float* __restrict__ tdt,
                     const float* __restrict__ dtw1, const float* __restrict__ dtb1,
                     const float* __restrict__ dtw2, const float* __restrict__ dtb2,
                     float* __restrict__ dsp_all){
  __shared__ float td[RR][64];
  int l0 = blockIdx.x * 64;
  int mbk = blockIdx.y;
  int k = mbk % KK; int m = (mbk / KK) / BN;
  const float* src = tdt + (size_t)mbk * RR * LL;
  for (int idx = threadIdx.x; idx < RR * 64; idx += blockDim.x){
    int r = idx >> 6, ll = idx & 63;
    td[r][ll] = src[r * LL + l0 + ll];
  }
  __syncthreads();
  const float* dtw = (m == 0 ? dtw1 : dtw2);
  const float* dtb = (m == 0 ? dtb1 : dtb2);
  for (int idx = threadIdx.x; idx < DIN * 64; idx += blockDim.x){
    int dd = idx >> 6, ll = idx & 63;
    int kd = k * DIN + dd;
    const float* w = dtw + kd * RR;
    float a = dtb[kd];
    #pragma unroll
    for (int r = 0; r < RR; ++r) a += w[r] * td[r][ll];
    dsp_all[((size_t)mbk * DIN + dd) * LL + l0 + ll] = softplusf_(a);
  }
}

// ---------------- K6: chunked parallel selective scan -------------------
// one wave per chain; lane g owns 25 steps, all 16 states in registers.
// grid: 768 blocks of 256 (4 chains/block). y_px layout [mbk][d][pixel]
__global__ void __launch_bounds__(256) k_scan(
    const float* __restrict__ x_act, const float* __restrict__ x_actT,
    const float* __restrict__ dsp_all, const float* __restrict__ Bt,
    const float* __restrict__ Ct,
    const float* __restrict__ Alog1, const float* __restrict__ Alog2,
    const float* __restrict__ D1, const float* __restrict__ D2,
    float* __restrict__ y_px){
  __shared__ float ystage[4][LL + HH];    // padded: index l + l/40
  const int CH = LL / 64;                 // 25 steps per lane
  int wv   = threadIdx.x >> 6;
  int lane = threadIdx.x & 63;
  int chain = blockIdx.x * 4 + wv;        // = (mb*KK + k)*DIN + d
  int d   = chain % DIN;
  int mbk = chain / DIN;
  int k   = mbk % KK;
  int mb  = mbk / KK;
  int m = mb / BN, b = mb % BN;
  int kd = k * DIN + d;
  bool rev = (k >= 2);

  const float* Alog = (m == 0 ? Alog1 : Alog2) + kd * NS;
  float An[NS];
  #pragma unroll
  for (int n = 0; n < NS; ++n) An[n] = -__expf(Alog[n]);
  float Dv = (m == 0 ? D2 : D1)[kd];

  const float* dsp = dsp_all + (size_t)chain * LL;
  const float* Bp  = Bt + (size_t)mbk * LL * NS;
  int mbk_o = ((1 - m) * BN + b) * KK + k;      // other modality's C
  const float* Cp  = Ct + (size_t)mbk_o * LL * NS;
  const float* up  = ((k & 1) ? x_actT : x_act) + ((size_t)mb * DIN + d) * LL;

  int l0 = lane * CH;
  float h[NS], aP[NS];
  #pragma unroll
  for (int n = 0; n < NS; ++n){ h[n] = 0.f; aP[n] = 1.f; }

  // phase 1: local chunk scan -> (prod dA, h_local_end)
  for (int s = 0; s < CH; ++s){
    int l = l0 + s;
    float dt = dsp[l];
    float u  = up[rev ? (LL - 1 - l) : l];
    float du = dt * u;
    const float4* B4 = reinterpret_cast<const float4*>(Bp + (size_t)l * NS);
    float4 q0 = B4[0], q1 = B4[1], q2 = B4[2], q3 = B4[3];
    float Bv[NS] = {q0.x,q0.y,q0.z,q0.w, q1.x,q1.y,q1.z,q1.w,
                    q2.x,q2.y,q2.z,q2.w, q3.x,q3.y,q3.z,q3.w};
    #pragma unroll
    for (int n = 0; n < NS; ++n){
      float dA = __expf(dt * An[n]);
      aP[n] *= dA;
      h[n] = dA * h[n] + du * Bv[n];
    }
  }
  // Kogge-Stone inclusive scan of (aP,h) across 64 lanes (chunk order)
  #pragma unroll
  for (int off = 1; off < 64; off <<= 1){
    #pragma unroll
    for (int n = 0; n < NS; ++n){
      float ap = __shfl_up(aP[n], off);
      float bp = __shfl_up(h[n],  off);
      if (lane >= off){
        h[n]  = aP[n] * bp + h[n];
        aP[n] = aP[n] * ap;
      }
    }
  }
  // carry-in for this chunk = inclusive result of previous lane
  #pragma unroll
  for (int n = 0; n < NS; ++n){
    float v = __shfl_up(h[n], 1);
    h[n] = (lane == 0) ? 0.f : v;
  }
  // phase 2: rescan with carry, emit y into LDS (scan-step order, padded)
  for (int s = 0; s < CH; ++s){
    int l = l0 + s;
    float dt = dsp[l];
    float u  = up[rev ? (LL - 1 - l) : l];
    float du = dt * u;
    const float4* B4 = reinterpret_cast<const float4*>(Bp + (size_t)l * NS);
    float4 q0 = B4[0], q1 = B4[1], q2 = B4[2], q3 = B4[3];
    float Bv[NS] = {q0.x,q0.y,q0.z,q0.w, q1.x,q1.y,q1.z,q1.w,
                    q2.x,q2.y,q2.z,q2.w, q3.x,q3.y,q3.z,q3.w};
    const float4* C4 = reinterpret_cast<const float4*>(Cp + (size_t)l * NS);
    float4 c0 = C4[0], c1 = C4[1], c2 = C4[2], c3 = C4[3];
    float Cv[NS] = {c0.x,c0.y,c0.z,c0.w, c1.x,c1.y,c1.z,c1.w,
                    c2.x,c2.y,c2.z,c2.w, c3.x,c3.y,c3.z,c3.w};
    float y = 0.f;
    #pragma unroll
    for (int n = 0; n < NS; ++n){
      float dA = __expf(dt * An[n]);
      h[n] = dA * h[n] + du * Bv[n];
      y += h[n] * Cv[n];
    }
    ystage[wv][l + l / WW] = y + Dv * u;
  }
  __syncthreads();
  // flush in PIXEL order: fold reversal (k>=2) + transpose (k odd) here.
  // all 4 chains of this block share the same k.
  for (int idx = threadIdx.x; idx < 4 * LL; idx += 256){
    int c = idx / LL, q = idx - c * LL;
    int l;
    if      (k == 0) l = q;
    else if (k == 1) l = (q % WW) * WW + q / WW;
    else if (k == 2) l = LL - 1 - q;
    else             { int qt = (q % WW) * WW + q / WW; l = LL - 1 - qt; }
    y_px[(size_t)(blockIdx.x * 4 + c) * LL + q] = ystage[c][l + l / WW];
  }
}

// ---------------- K7: merge (4 coalesced adds) + LayerNorm + cross SE ---
// grid: (L/64, 2*B), block 256. y_final layout [mb][p][d]
__global__ void k_merge(const float* __restrict__ y_px, const float* __restrict__ exc,
                        const float* __restrict__ n1g, const float* __restrict__ n1b,
                        const float* __restrict__ n2g, const float* __restrict__ n2b,
                        float* __restrict__ y_final){
  __shared__ float acc[DIN][65];
  __shared__ float mu_s[64], inv_s[64];
  int p0 = blockIdx.x * 64;
  int mb = blockIdx.y; int m = mb / BN, b = mb % BN;
  const float* yb = y_px + (size_t)mb * KK * DIN * LL;
  for (int idx = threadIdx.x; idx < DIN * 64; idx += 256){
    int dd = idx >> 6, pp = idx & 63;
    size_t o = (size_t)dd * LL + p0 + pp;
    float v = yb[o] + yb[(size_t)DIN * LL + o]
            + yb[2 * (size_t)DIN * LL + o] + yb[3 * (size_t)DIN * LL + o];
    acc[dd][pp] = v;
  }
  __syncthreads();
  if (threadIdx.x < 64){
    int pp = threadIdx.x;
    float s = 0.f, s2 = 0.f;
    for (int dd = 0; dd < DIN; ++dd){ float v = acc[dd][pp]; s += v; s2 += v * v; }
    float mu  = s * (1.0f / DIN);
    float var = s2 * (1.0f / DIN) - mu * mu;
    mu_s[pp] = mu; inv_s[pp] = rsqrtf(var + 1e-5f);
  }
  __syncthreads();
  const float* g  = (m == 0 ? n1g : n2g);
  const float* bb = (m == 0 ? n1b : n2b);
  const float* ex = exc + ((1 - m) * BN + b) * DIN;
  for (int idx = threadIdx.x; idx < DIN * 64; idx += 256){
    int pp = idx / DIN, dd = idx - pp * DIN;
    float v = (acc[dd][pp] - mu_s[pp]) * inv_s[pp] * g[dd] + bb[dd];
    v *= ex[dd];
    y_final[((size_t)mb * LL + p0 + pp) * DIN + dd] = v;
  }
}

// ---------------- K8: out_proj (96 x 384) ----------------
// grid: (L/32, B), block 256. LDS tile padded to stride 385
__global__ void k_out(const float* __restrict__ y_final, const float* __restrict__ wout,
                      float* __restrict__ out){
  __shared__ float yt[32 * 385];
  int p0 = blockIdx.x * 32;
  int b  = blockIdx.y;
  for (int idx = threadIdx.x; idx < 32 * 384; idx += blockDim.x){
    int pp = idx / 384, c = idx % 384;
    int m = c / DIN, d = c % DIN;
    yt[pp * 385 + c] = y_final[(((size_t)(m * BN + b)) * LL + p0 + pp) * DIN + d];
  }
  __syncthreads();
  int pp = threadIdx.x & 31;
  int og = threadIdx.x >> 5;
  #pragma unroll
  for (int i = 0; i < 12; ++i){
    int o = og * 12 + i;
    const float* wr = wout + o * 2 * DIN;
    float acc = 0.f;
    #pragma unroll 8
    for (int c = 0; c < 2 * DIN; ++c) acc += wr[c] * yt[pp * 385 + c];
    out[((size_t)b * CIN + o) * LL + p0 + pp] = acc;
  }
}

extern "C" void kernel_launch(void* const* d_in, const int* in_sizes, int n_in,
                              void* d_out, int out_size, void* d_ws, size_t ws_size,
                              hipStream_t stream){
  const float* x_rgb   = (const float*)d_in[0];
  const float* x_e     = (const float*)d_in[1];
  const float* in_w    = (const float*)d_in[2];
  const float* in_mx_w = (const float*)d_in[3];
  const float* conv_w  = (const float*)d_in[4];
  const float* conv_b  = (const float*)d_in[5];
  const float* xp1     = (const float*)d_in[6];
  const float* xp2     = (const float*)d_in[7];
  const float* dtw1    = (const float*)d_in[8];
  const float* dtb1    = (const float*)d_in[9];
  const float* dtw2    = (const float*)d_in[10];
  const float* dtb2    = (const float*)d_in[11];
  const float* Alog1   = (const float*)d_in[12];
  const float* Alog2   = (const float*)d_in[13];
  const float* D1      = (const float*)d_in[14];
  const float* D2      = (const float*)d_in[15];
  const float* n1g     = (const float*)d_in[16];
  const float* n1b     = (const float*)d_in[17];
  const float* n2g     = (const float*)d_in[18];
  const float* n2b     = (const float*)d_in[19];
  const float* fc1_w1  = (const float*)d_in[20];
  const float* fc1_w2  = (const float*)d_in[21];
  const float* fc2_w1  = (const float*)d_in[22];
  const float* fc2_w2  = (const float*)d_in[23];
  const float* wout    = (const float*)d_in[24];

  float* ws = (float*)d_ws;
  // region plan (floats), total 13,262,336 (= 53.0 MB, same as round 1):
  //   [0,          1228800) x_act
  //   [1228800,    2457600) x_actT
  //   [2457600,    3686400) xproj   (k1->k2 only)
  //   [2457600,    7372800) y_px    (k_scan out; aliases dead xproj)
  //   [7372800,   12288000) dsp     (k_dt->k_scan); y_final aliases after scan
  //   [12288000,  12697600) Bt
  //   [12697600,  13107200) Ct
  //   [13107200,  13260800) tdt
  //   [13260800,  13261568) sq
  //   [13261568,  13262336) exc
  float* x_act   = ws;
  float* x_actT  = ws + 1228800;
  float* xproj   = ws + 2457600;
  float* y_px    = ws + 2457600;
  float* dsp     = ws + 7372800;
  float* y_final = ws + 7372800;
  float* Bt      = ws + 12288000;
  float* Ct      = ws + 12697600;
  float* tdt     = ws + 13107200;
  float* sq      = ws + 13260800;
  float* exc     = ws + 13261568;

  k_inproj<<<dim3(LL / 64, 2 * BN), 256, 0, stream>>>(x_rgb, x_e, in_w, in_mx_w, xproj);
  k_conv  <<<dim3(DIN, 2 * BN), 256, 0, stream>>>(xproj, conv_w, conv_b, x_act, x_actT, sq);
  k_se    <<<2 * BN, DIN, 0, stream>>>(sq, fc1_w1, fc1_w2, fc2_w1, fc2_w2, exc);
  k_xproj <<<dim3(LL / 64, KK, 2 * BN), 256, 0, stream>>>(x_act, x_actT, xp1, xp2, tdt, Bt, Ct);
  k_dt    <<<dim3(LL / 64, 16), 256, 0, stream>>>(tdt, dtw1, dtb1, dtw2, dtb2, dsp);
  k_scan  <<<768, 256, 0, stream>>>(x_act, x_actT, dsp, Bt, Ct,
                                    Alog1, Alog2, D1, D2, y_px);
  k_merge <<<dim3(LL / 64, 2 * BN), 256, 0, stream>>>(y_px, exc, n1g, n1b, n2g, n2b, y_final);
  k_out   <<<dim3(LL / 32, BN), 256, 0, stream>>>(y_final, wout, (float*)d_out);
}

// Round 3
// 287.059 us; speedup vs baseline: 4.9684x; 1.4557x over previous
//
#include <hip/hip_runtime.h>
#include <math.h>

#define BN   2
#define CIN  96
#define HH   40
#define WW   40
#define LL   1600
#define DIN  192
#define NS   16
#define RR   6
#define KK   4
#define CH   25   // chunk length per lane (LL/64)

__device__ __forceinline__ float sigmoidf_(float x){ return 1.0f/(1.0f+expf(-x)); }
__device__ __forceinline__ float softplusf_(float x){ return x > 20.0f ? x : log1pf(expf(x)); }

// ---------------- K1: in_proj (1x1) for both modalities ----------------
// grid: (L/32, 2*B), block 256. xproj layout [mb][o][p]
__global__ void k_inproj(const float* __restrict__ x_rgb, const float* __restrict__ x_e,
                         const float* __restrict__ w_rgb, const float* __restrict__ w_e,
                         float* __restrict__ xproj){
  __shared__ float xin[CIN][32];
  int l0 = blockIdx.x * 32;
  int mb = blockIdx.y;            // m*BN + b
  int m = mb / BN, b = mb % BN;
  const float* xsrc = (m == 0 ? x_rgb : x_e) + (size_t)b * CIN * LL;
  const float* w    = (m == 0 ? w_rgb : w_e);
  for (int idx = threadIdx.x; idx < CIN * 32; idx += blockDim.x){
    int c = idx >> 5, ll = idx & 31;
    xin[c][ll] = xsrc[c * LL + l0 + ll];
  }
  __syncthreads();
  for (int oidx = threadIdx.x; oidx < DIN * 32; oidx += blockDim.x){
    int o = oidx >> 5, ll = oidx & 31;
    const float* wr = w + o * CIN;
    float acc = 0.f;
    #pragma unroll 8
    for (int c = 0; c < CIN; ++c) acc += wr[c] * xin[c][ll];
    xproj[((size_t)mb * DIN + o) * LL + l0 + ll] = acc;
  }
}

// ------ K2: depthwise 3x3 + bias + SiLU; emit x_act, x_actT, u_ch, SE mean ---
// grid: (DIN, 2*B), block 256
__global__ void k_conv(const float* __restrict__ xproj, const float* __restrict__ conv_w,
                       const float* __restrict__ conv_b, float* __restrict__ x_act,
                       float* __restrict__ x_actT, float* __restrict__ u_chA,
                       float* __restrict__ u_chT, float* __restrict__ sq){
  __shared__ float pl[LL];
  __shared__ float sact[LL + HH];    // padded: index l + l/40
  __shared__ float red[4];
  int d  = blockIdx.x;
  int mb = blockIdx.y;
  const float* src = xproj + ((size_t)mb * DIN + d) * LL;
  for (int p = threadIdx.x; p < LL; p += blockDim.x) pl[p] = src[p];
  __syncthreads();
  float cw[9];
  #pragma unroll
  for (int j = 0; j < 9; ++j) cw[j] = conv_w[d * 9 + j];
  float bias = conv_b[d];
  float* dst = x_act + ((size_t)mb * DIN + d) * LL;
  float lsum = 0.f;
  for (int p = threadIdx.x; p < LL; p += blockDim.x){
    int py = p / WW, px = p % WW;
    float acc = bias;
    #pragma unroll
    for (int dy = -1; dy <= 1; ++dy){
      int yy = py + dy;
      if (yy < 0 || yy >= HH) continue;
      #pragma unroll
      for (int dx = -1; dx <= 1; ++dx){
        int xx = px + dx;
        if (xx < 0 || xx >= WW) continue;
        acc += cw[(dy + 1) * 3 + (dx + 1)] * pl[yy * WW + xx];
      }
    }
    float s = acc * sigmoidf_(acc);
    dst[p] = s;
    sact[p + p / WW] = s;
    lsum += s;
  }
  #pragma unroll
  for (int off = 32; off; off >>= 1) lsum += __shfl_down(lsum, off);
  if ((threadIdx.x & 63) == 0) red[threadIdx.x >> 6] = lsum;
  __syncthreads();
  if (threadIdx.x == 0)
    sq[mb * DIN + d] = (red[0] + red[1] + red[2] + red[3]) * (1.0f / LL);
  size_t po = ((size_t)mb * DIN + d) * LL;
  float* dstT = x_actT + po;
  float* uA   = u_chA + po;
  float* uT   = u_chT + po;
  for (int q = threadIdx.x; q < LL; q += blockDim.x){
    // transposed plane (row-major in q)
    int lt = (q % WW) * WW + q / WW;
    dstT[q] = sact[lt + lt / WW];
    // chunk-order planes: q = s*64+g  <->  l = g*25+s
    int l = (q & 63) * CH + (q >> 6);
    uA[q] = sact[l + l / WW];
    int pt = (l % WW) * WW + l / WW;
    uT[q] = sact[pt + pt / WW];
  }
}

// ---------------- K3: cross squeeze-excitation ----------------
// grid: 2*B blocks of 192 threads. exc[mb][d]
__global__ void k_se(const float* __restrict__ sq,
                     const float* __restrict__ fc1_w1, const float* __restrict__ fc1_w2,
                     const float* __restrict__ fc2_w1, const float* __restrict__ fc2_w2,
                     float* __restrict__ exc){
  __shared__ float s[DIN];
  __shared__ float hid[12];
  int mb = blockIdx.x; int m = mb / BN;
  const float* w1 = (m == 0 ? fc1_w1 : fc2_w1);
  const float* w2 = (m == 0 ? fc1_w2 : fc2_w2);
  int t = threadIdx.x;
  s[t] = sq[mb * DIN + t];
  __syncthreads();
  if (t < 12){
    float a = 0.f;
    for (int c = 0; c < DIN; ++c) a += w1[t * DIN + c] * s[c];
    hid[t] = a * sigmoidf_(a);
  }
  __syncthreads();
  float e = 0.f;
  #pragma unroll
  for (int j = 0; j < 12; ++j) e += w2[t * 12 + j] * hid[j];
  exc[mb * DIN + t] = sigmoidf_(e);
}

// ------ K4: x_proj -> tdt rows; B/C in CHUNK layout [mbk][q][n] ---------
// grid: (L/64, K, 2*B), block 256
__global__ void k_xproj(const float* __restrict__ x_act, const float* __restrict__ x_actT,
                        const float* __restrict__ xp1, const float* __restrict__ xp2,
                        float* __restrict__ tdt, float* __restrict__ B_ch,
                        float* __restrict__ C_ch){
  __shared__ float xs_t[DIN][64];
  int l0 = blockIdx.x * 64;
  int k  = blockIdx.y;
  int mb = blockIdx.z; int m = mb / BN;
  const float* xw = (m == 0 ? xp1 : xp2) + k * 38 * DIN;
  const float* xa = ((k & 1) ? x_actT : x_act) + (size_t)mb * DIN * LL;
  bool rev = (k >= 2);
  for (int idx = threadIdx.x; idx < DIN * 64; idx += blockDim.x){
    int dd = idx >> 6, ll = idx & 63;
    int l = l0 + ll; if (rev) l = LL - 1 - l;
    xs_t[dd][ll] = xa[dd * LL + l];
  }
  __syncthreads();
  int mbk = mb * KK + k;
  for (int oidx = threadIdx.x; oidx < 38 * 64; oidx += blockDim.x){
    int c = oidx >> 6, ll = oidx & 63;
    const float* wr = xw + c * DIN;
    float acc = 0.f;
    #pragma unroll 8
    for (int dd = 0; dd < DIN; ++dd) acc += wr[dd] * xs_t[dd][ll];
    int l = l0 + ll;
    if (c < RR){
      tdt[((size_t)mbk * RR + c) * LL + l] = acc;
    } else {
      int q = (l % CH) * 64 + l / CH;     // chunk-order index
      if (c < RR + NS)  B_ch[((size_t)mbk * LL + q) * NS + (c - RR)] = acc;
      else              C_ch[((size_t)mbk * LL + q) * NS + (c - RR - NS)] = acc;
    }
  }
}

// ------ K5: dt projection + softplus -> dsp_ch[mbk][d][q] (chunk order) --
// grid: (16, 12), block 256; each block: one mbk, 16 d's, all q
__global__ void k_dt(const float* __restrict__ tdt,
                     const float* __restrict__ dtw1, const float* __restrict__ dtb1,
                     const float* __restrict__ dtw2, const float* __restrict__ dtb2,
                     float* __restrict__ dsp_all){
  __shared__ float td[RR * LL];          // 38.4 KB
  int mbk = blockIdx.x;
  int dg  = blockIdx.y;
  int k = mbk % KK; int m = (mbk / KK) / BN;
  const float* src = tdt + (size_t)mbk * RR * LL;
  for (int i = threadIdx.x; i < RR * LL; i += 256) td[i] = src[i];
  __syncthreads();
  const float* dtw = (m == 0 ? dtw1 : dtw2);
  const float* dtb = (m == 0 ? dtb1 : dtb2);
  for (int oi = threadIdx.x; oi < 16 * LL; oi += 256){
    int dl = oi / LL, q = oi - dl * LL;
    int dd = dg * 16 + dl;
    int kd = k * DIN + dd;
    int l = (q & 63) * CH + (q >> 6);
    const float* w = dtw + kd * RR;
    float a = dtb[kd];
    #pragma unroll
    for (int r = 0; r < RR; ++r) a += w[r] * td[r * LL + l];
    dsp_all[((size_t)mbk * DIN + dd) * LL + q] = softplusf_(a);
  }
}

// ---------------- K6: chunked parallel selective scan (coalesced) --------
// one wave per chain; lane g owns scan range [25g, 25g+25); all reads are
// contiguous across lanes at each step (chunk-order storage).
// grid: 768 blocks of 256 (4 chains/block). y_px layout [chain][pixel]
__global__ void __launch_bounds__(256) k_scan(
    const float* __restrict__ u_chA, const float* __restrict__ u_chT,
    const float* __restrict__ dsp_all, const float* __restrict__ B_ch,
    const float* __restrict__ C_ch,
    const float* __restrict__ Alog1, const float* __restrict__ Alog2,
    const float* __restrict__ D1, const float* __restrict__ D2,
    float* __restrict__ y_px){
  __shared__ float ystage[4][LL + HH];    // padded: index l + l/40
  int wv   = threadIdx.x >> 6;
  int lane = threadIdx.x & 63;
  int chain = blockIdx.x * 4 + wv;        // = (mb*KK + k)*DIN + d
  int d   = chain % DIN;
  int mbk = chain / DIN;
  int k   = mbk % KK;
  int mb  = mbk / KK;
  int m = mb / BN, b = mb % BN;
  int kd = k * DIN + d;
  bool rev = (k >= 2);

  const float* Alog = (m == 0 ? Alog1 : Alog2) + kd * NS;
  float An[NS];
  #pragma unroll
  for (int n = 0; n < NS; ++n) An[n] = -__expf(Alog[n]);
  float Dv = (m == 0 ? D2 : D1)[kd];

  const float* dsp = dsp_all + (size_t)chain * LL;
  const float* Bp  = B_ch + (size_t)mbk * LL * NS;
  int mbk_o = ((1 - m) * BN + b) * KK + k;      // other modality's C
  const float* Cp  = C_ch + (size_t)mbk_o * LL * NS;
  const float* urow = ((k & 1) ? u_chT : u_chA) + ((size_t)mb * DIN + d) * LL;

  float h[NS], aP[NS];
  #pragma unroll
  for (int n = 0; n < NS; ++n){ h[n] = 0.f; aP[n] = 1.f; }

  // phase 1: local chunk scan -> (prod dA, h_local_end)
  for (int s = 0; s < CH; ++s){
    int q = s * 64 + lane;
    float dt = dsp[q];
    float u  = urow[rev ? ((CH - 1 - s) * 64 + (63 - lane)) : q];
    float du = dt * u;
    const float4* B4 = reinterpret_cast<const float4*>(Bp + (size_t)q * NS);
    float4 q0 = B4[0], q1 = B4[1], q2 = B4[2], q3 = B4[3];
    float Bv[NS] = {q0.x,q0.y,q0.z,q0.w, q1.x,q1.y,q1.z,q1.w,
                    q2.x,q2.y,q2.z,q2.w, q3.x,q3.y,q3.z,q3.w};
    #pragma unroll
    for (int n = 0; n < NS; ++n){
      float dA = __expf(dt * An[n]);
      aP[n] *= dA;
      h[n] = dA * h[n] + du * Bv[n];
    }
  }
  // Kogge-Stone inclusive scan of (aP,h) across 64 lanes (chunk order)
  #pragma unroll
  for (int off = 1; off < 64; off <<= 1){
    #pragma unroll
    for (int n = 0; n < NS; ++n){
      float ap = __shfl_up(aP[n], off);
      float bp = __shfl_up(h[n],  off);
      if (lane >= off){
        h[n]  = aP[n] * bp + h[n];
        aP[n] = aP[n] * ap;
      }
    }
  }
  // carry-in for this chunk = inclusive result of previous lane
  #pragma unroll
  for (int n = 0; n < NS; ++n){
    float v = __shfl_up(h[n], 1);
    h[n] = (lane == 0) ? 0.f : v;
  }
  // phase 2: rescan with carry, emit y into LDS (scan-step order, padded)
  for (int s = 0; s < CH; ++s){
    int q = s * 64 + lane;
    float dt = dsp[q];
    float u  = urow[rev ? ((CH - 1 - s) * 64 + (63 - lane)) : q];
    float du = dt * u;
    const float4* B4 = reinterpret_cast<const float4*>(Bp + (size_t)q * NS);
    float4 b0 = B4[0], b1 = B4[1], b2 = B4[2], b3 = B4[3];
    float Bv[NS] = {b0.x,b0.y,b0.z,b0.w, b1.x,b1.y,b1.z,b1.w,
                    b2.x,b2.y,b2.z,b2.w, b3.x,b3.y,b3.z,b3.w};
    const float4* C4 = reinterpret_cast<const float4*>(Cp + (size_t)q * NS);
    float4 c0 = C4[0], c1 = C4[1], c2 = C4[2], c3 = C4[3];
    float Cv[NS] = {c0.x,c0.y,c0.z,c0.w, c1.x,c1.y,c1.z,c1.w,
                    c2.x,c2.y,c2.z,c2.w, c3.x,c3.y,c3.z,c3.w};
    float y = 0.f;
    #pragma unroll
    for (int n = 0; n < NS; ++n){
      float dA = __expf(dt * An[n]);
      h[n] = dA * h[n] + du * Bv[n];
      y += h[n] * Cv[n];
    }
    int l = lane * CH + s;
    ystage[wv][l + l / WW] = y + Dv * u;
  }
  __syncthreads();
  // flush in PIXEL order: fold reversal (k>=2) + transpose (k odd) here.
  // all 4 chains of this block share the same k.
  for (int idx = threadIdx.x; idx < 4 * LL; idx += 256){
    int c = idx / LL, qq = idx - c * LL;
    int l;
    if      (k == 0) l = qq;
    else if (k == 1) l = (qq % WW) * WW + qq / WW;
    else if (k == 2) l = LL - 1 - qq;
    else             { int qt = (qq % WW) * WW + qq / WW; l = LL - 1 - qt; }
    y_px[(size_t)(blockIdx.x * 4 + c) * LL + qq] = ystage[c][l + l / WW];
  }
}

// ---------------- K7: merge (4 coalesced adds) + LayerNorm + cross SE ---
// grid: (L/64, 2*B), block 256. y_final layout [mb][p][d]
__global__ void k_merge(const float* __restrict__ y_px, const float* __restrict__ exc,
                        const float* __restrict__ n1g, const float* __restrict__ n1b,
                        const float* __restrict__ n2g, const float* __restrict__ n2b,
                        float* __restrict__ y_final){
  __shared__ float acc[DIN][65];
  __shared__ float mu_s[64], inv_s[64];
  int p0 = blockIdx.x * 64;
  int mb = blockIdx.y; int m = mb / BN, b = mb % BN;
  const float* yb = y_px + (size_t)mb * KK * DIN * LL;
  for (int idx = threadIdx.x; idx < DIN * 64; idx += 256){
    int dd = idx >> 6, pp = idx & 63;
    size_t o = (size_t)dd * LL + p0 + pp;
    float v = yb[o] + yb[(size_t)DIN * LL + o]
            + yb[2 * (size_t)DIN * LL + o] + yb[3 * (size_t)DIN * LL + o];
    acc[dd][pp] = v;
  }
  __syncthreads();
  if (threadIdx.x < 64){
    int pp = threadIdx.x;
    float s = 0.f, s2 = 0.f;
    for (int dd = 0; dd < DIN; ++dd){ float v = acc[dd][pp]; s += v; s2 += v * v; }
    float mu  = s * (1.0f / DIN);
    float var = s2 * (1.0f / DIN) - mu * mu;
    mu_s[pp] = mu; inv_s[pp] = rsqrtf(var + 1e-5f);
  }
  __syncthreads();
  const float* g  = (m == 0 ? n1g : n2g);
  const float* bb = (m == 0 ? n1b : n2b);
  const float* ex = exc + ((1 - m) * BN + b) * DIN;
  for (int idx = threadIdx.x; idx < DIN * 64; idx += 256){
    int pp = idx / DIN, dd = idx - pp * DIN;
    float v = (acc[dd][pp] - mu_s[pp]) * inv_s[pp] * g[dd] + bb[dd];
    v *= ex[dd];
    y_final[((size_t)mb * LL + p0 + pp) * DIN + dd] = v;
  }
}

// ---------------- K8: out_proj (96 x 384) ----------------
// grid: (L/16, B), block 256. LDS tile padded to stride 385
__global__ void k_out(const float* __restrict__ y_final, const float* __restrict__ wout,
                      float* __restrict__ out){
  __shared__ float yt[16 * 385];
  int p0 = blockIdx.x * 16;
  int b  = blockIdx.y;
  for (int idx = threadIdx.x; idx < 16 * 384; idx += blockDim.x){
    int pp = idx / 384, c = idx % 384;
    int m = c / DIN, d = c % DIN;
    yt[pp * 385 + c] = y_final[(((size_t)(m * BN + b)) * LL + p0 + pp) * DIN + d];
  }
  __syncthreads();
  int pp = threadIdx.x & 15;
  int og = threadIdx.x >> 4;     // 0..15
  #pragma unroll
  for (int i = 0; i < 6; ++i){
    int o = og * 6 + i;
    const float* wr = wout + o * 2 * DIN;
    float acc = 0.f;
    #pragma unroll 8
    for (int c = 0; c < 2 * DIN; ++c) acc += wr[c] * yt[pp * 385 + c];
    out[((size_t)b * CIN + o) * LL + p0 + pp] = acc;
  }
}

extern "C" void kernel_launch(void* const* d_in, const int* in_sizes, int n_in,
                              void* d_out, int out_size, void* d_ws, size_t ws_size,
                              hipStream_t stream){
  const float* x_rgb   = (const float*)d_in[0];
  const float* x_e     = (const float*)d_in[1];
  const float* in_w    = (const float*)d_in[2];
  const float* in_mx_w = (const float*)d_in[3];
  const float* conv_w  = (const float*)d_in[4];
  const float* conv_b  = (const float*)d_in[5];
  const float* xp1     = (const float*)d_in[6];
  const float* xp2     = (const float*)d_in[7];
  const float* dtw1    = (const float*)d_in[8];
  const float* dtb1    = (const float*)d_in[9];
  const float* dtw2    = (const float*)d_in[10];
  const float* dtb2    = (const float*)d_in[11];
  const float* Alog1   = (const float*)d_in[12];
  const float* Alog2   = (const float*)d_in[13];
  const float* D1      = (const float*)d_in[14];
  const float* D2      = (const float*)d_in[15];
  const float* n1g     = (const float*)d_in[16];
  const float* n1b     = (const float*)d_in[17];
  const float* n2g     = (const float*)d_in[18];
  const float* n2b     = (const float*)d_in[19];
  const float* fc1_w1  = (const float*)d_in[20];
  const float* fc1_w2  = (const float*)d_in[21];
  const float* fc2_w1  = (const float*)d_in[22];
  const float* fc2_w2  = (const float*)d_in[23];
  const float* wout    = (const float*)d_in[24];

  float* ws = (float*)d_ws;
  // region plan (floats), total 13,262,336 (= 53.0 MB):
  //   [0,        1228800) u_chA   (k_conv -> k_scan)
  //   [1228800,  2457600) u_chT   (k_conv -> k_scan)
  //   [2457600,  3686400) x_act   (k_conv -> k_xproj); y_final aliases later
  //   [3686400,  4915200) x_actT  (k_conv -> k_xproj)
  //   [4915200,  6144000) xproj   (k_inproj -> k_conv)
  //   [2457600,  7372800) dsp_ch  (k_dt -> k_scan; over dead x_act/x_actT/xproj)
  //   [7372800, 12288000) y_px    (k_scan -> k_merge)
  //   [12288000,12697600) B_ch
  //   [12697600,13107200) C_ch
  //   [13107200,13260800) tdt
  //   [13260800,13261568) sq
  //   [13261568,13262336) exc
  float* u_chA   = ws;
  float* u_chT   = ws + 1228800;
  float* x_act   = ws + 2457600;
  float* x_actT  = ws + 3686400;
  float* xproj   = ws + 4915200;
  float* dsp     = ws + 2457600;
  float* y_final = ws + 2457600;
  float* y_px    = ws + 7372800;
  float* B_ch    = ws + 12288000;
  float* C_ch    = ws + 12697600;
  float* tdt     = ws + 13107200;
  float* sq      = ws + 13260800;
  float* exc     = ws + 13261568;

  k_inproj<<<dim3(LL / 32, 2 * BN), 256, 0, stream>>>(x_rgb, x_e, in_w, in_mx_w, xproj);
  k_conv  <<<dim3(DIN, 2 * BN), 256, 0, stream>>>(xproj, conv_w, conv_b,
                                                  x_act, x_actT, u_chA, u_chT, sq);
  k_se    <<<2 * BN, DIN, 0, stream>>>(sq, fc1_w1, fc1_w2, fc2_w1, fc2_w2, exc);
  k_xproj <<<dim3(LL / 64, KK, 2 * BN), 256, 0, stream>>>(x_act, x_actT, xp1, xp2,
                                                          tdt, B_ch, C_ch);
  k_dt    <<<dim3(16, 12), 256, 0, stream>>>(tdt, dtw1, dtb1, dtw2, dtb2, dsp);
  k_scan  <<<768, 256, 0, stream>>>(u_chA, u_chT, dsp, B_ch, C_ch,
                                    Alog1, Alog2, D1, D2, y_px);
  k_merge <<<dim3(LL / 64, 2 * BN), 256, 0, stream>>>(y_px, exc, n1g, n1b, n2g, n2b, y_final);
  k_out   <<<dim3(LL / 16, BN), 256, 0, stream>>>(y_final, wout, (float*)d_out);
}

// Round 4
// 238.914 us; speedup vs baseline: 5.9697x; 1.2015x over previous
//
#include <hip/hip_runtime.h>
#include <math.h>

#define BN   2
#define CIN  96
#define HH   40
#define WW   40
#define LL   1600
#define DIN  192
#define NS   16
#define RR   6
#define KK   4
#define CH   25   // chunk length per lane (LL/64)

__device__ __forceinline__ float sigmoidf_(float x){ return 1.0f/(1.0f+expf(-x)); }
__device__ __forceinline__ float softplusf_(float x){ return x > 20.0f ? x : log1pf(expf(x)); }

// ---------------- K1: in_proj (1x1) for both modalities ----------------
// grid: (L/16, 2*B), block 256. xproj layout [mb][o][p]
__global__ void k_inproj(const float* __restrict__ x_rgb, const float* __restrict__ x_e,
                         const float* __restrict__ w_rgb, const float* __restrict__ w_e,
                         float* __restrict__ xproj){
  __shared__ float xin[16][100];          // [px][c], padded row
  int l0 = blockIdx.x * 16;
  int mb = blockIdx.y;                    // m*BN + b
  int m = mb / BN, b = mb % BN;
  const float* xsrc = (m == 0 ? x_rgb : x_e) + (size_t)b * CIN * LL;
  const float* w    = (m == 0 ? w_rgb : w_e);
  for (int idx = threadIdx.x; idx < CIN * 16; idx += 256){
    int c = idx >> 4, px = idx & 15;
    xin[px][c] = xsrc[c * LL + l0 + px];
  }
  __syncthreads();
  int px = threadIdx.x & 15;
  int o0 = (threadIdx.x >> 4) * 12;       // 16 groups x 12 outputs
  float acc[12];
  #pragma unroll
  for (int i = 0; i < 12; ++i) acc[i] = 0.f;
  const float4* xv = reinterpret_cast<const float4*>(xin[px]);
  for (int cc = 0; cc < CIN / 4; ++cc){
    float4 x4 = xv[cc];
    #pragma unroll
    for (int i = 0; i < 12; ++i){
      float4 w4 = *reinterpret_cast<const float4*>(w + (o0 + i) * CIN + cc * 4);
      acc[i] += w4.x * x4.x + w4.y * x4.y + w4.z * x4.z + w4.w * x4.w;
    }
  }
  #pragma unroll
  for (int i = 0; i < 12; ++i)
    xproj[((size_t)mb * DIN + o0 + i) * LL + l0 + px] = acc[i];
}

// ------ K2: depthwise 3x3 + bias + SiLU; emit x_act, x_actT, u_ch, SE mean ---
// grid: (DIN, 2*B), block 256
__global__ void k_conv(const float* __restrict__ xproj, const float* __restrict__ conv_w,
                       const float* __restrict__ conv_b, float* __restrict__ x_act,
                       float* __restrict__ x_actT, float* __restrict__ u_chA,
                       float* __restrict__ u_chT, float* __restrict__ sq){
  __shared__ float pl[LL];
  __shared__ float sact[LL + HH];    // padded: index l + l/40
  __shared__ float red[4];
  int d  = blockIdx.x;
  int mb = blockIdx.y;
  const float* src = xproj + ((size_t)mb * DIN + d) * LL;
  for (int p = threadIdx.x; p < LL; p += blockDim.x) pl[p] = src[p];
  __syncthreads();
  float cw[9];
  #pragma unroll
  for (int j = 0; j < 9; ++j) cw[j] = conv_w[d * 9 + j];
  float bias = conv_b[d];
  float* dst = x_act + ((size_t)mb * DIN + d) * LL;
  float lsum = 0.f;
  for (int p = threadIdx.x; p < LL; p += blockDim.x){
    int py = p / WW, px = p % WW;
    float acc = bias;
    #pragma unroll
    for (int dy = -1; dy <= 1; ++dy){
      int yy = py + dy;
      if (yy < 0 || yy >= HH) continue;
      #pragma unroll
      for (int dx = -1; dx <= 1; ++dx){
        int xx = px + dx;
        if (xx < 0 || xx >= WW) continue;
        acc += cw[(dy + 1) * 3 + (dx + 1)] * pl[yy * WW + xx];
      }
    }
    float s = acc * sigmoidf_(acc);
    dst[p] = s;
    sact[p + p / WW] = s;
    lsum += s;
  }
  #pragma unroll
  for (int off = 32; off; off >>= 1) lsum += __shfl_down(lsum, off);
  if ((threadIdx.x & 63) == 0) red[threadIdx.x >> 6] = lsum;
  __syncthreads();
  if (threadIdx.x == 0)
    sq[mb * DIN + d] = (red[0] + red[1] + red[2] + red[3]) * (1.0f / LL);
  size_t po = ((size_t)mb * DIN + d) * LL;
  float* dstT = x_actT + po;
  float* uA   = u_chA + po;
  float* uT   = u_chT + po;
  for (int q = threadIdx.x; q < LL; q += blockDim.x){
    // transposed plane (row-major in q)
    int lt = (q % WW) * WW + q / WW;
    dstT[q] = sact[lt + lt / WW];
    // chunk-order planes: q = s*64+g  <->  l = g*25+s
    int l = (q & 63) * CH + (q >> 6);
    uA[q] = sact[l + l / WW];
    int pt = (l % WW) * WW + l / WW;
    uT[q] = sact[pt + pt / WW];
  }
}

// ------ K3: x_proj -> tdt_ch [mbk][r][q]; B/C in CHUNK layout [mbk][q][n] ---
// grid: (L/64, K, 2*B), block 256
__global__ void k_xproj(const float* __restrict__ x_act, const float* __restrict__ x_actT,
                        const float* __restrict__ xp1, const float* __restrict__ xp2,
                        float* __restrict__ tdt_ch, float* __restrict__ B_ch,
                        float* __restrict__ C_ch){
  __shared__ float xs_t[DIN][64];
  int l0 = blockIdx.x * 64;
  int k  = blockIdx.y;
  int mb = blockIdx.z; int m = mb / BN;
  const float* xw = (m == 0 ? xp1 : xp2) + k * 38 * DIN;
  const float* xa = ((k & 1) ? x_actT : x_act) + (size_t)mb * DIN * LL;
  bool rev = (k >= 2);
  for (int idx = threadIdx.x; idx < DIN * 64; idx += blockDim.x){
    int dd = idx >> 6, ll = idx & 63;
    int l = l0 + ll; if (rev) l = LL - 1 - l;
    xs_t[dd][ll] = xa[dd * LL + l];
  }
  __syncthreads();
  int mbk = mb * KK + k;
  for (int oidx = threadIdx.x; oidx < 38 * 64; oidx += blockDim.x){
    int c = oidx >> 6, ll = oidx & 63;
    const float* wr = xw + c * DIN;
    float acc = 0.f;
    #pragma unroll 8
    for (int dd = 0; dd < DIN; ++dd) acc += wr[dd] * xs_t[dd][ll];
    int l = l0 + ll;
    int q = (l % CH) * 64 + l / CH;     // chunk-order index
    if (c < RR)            tdt_ch[((size_t)mbk * RR + c) * LL + q] = acc;
    else if (c < RR + NS)  B_ch[((size_t)mbk * LL + q) * NS + (c - RR)] = acc;
    else                   C_ch[((size_t)mbk * LL + q) * NS + (c - RR - NS)] = acc;
  }
}

// ---------------- K4: chunked parallel selective scan, n-split ----------
// 2 waves per chain (each owns 8 of 16 states); dt-proj + softplus fused.
// grid: 1536 blocks of 256 (2 chains/block). y_px layout [chain][pixel]
__global__ void __launch_bounds__(256, 6) k_scan(
    const float* __restrict__ u_chA, const float* __restrict__ u_chT,
    const float* __restrict__ tdt_all, const float* __restrict__ B_ch,
    const float* __restrict__ C_ch,
    const float* __restrict__ Alog1, const float* __restrict__ Alog2,
    const float* __restrict__ D1, const float* __restrict__ D2,
    const float* __restrict__ dtw1, const float* __restrict__ dtb1,
    const float* __restrict__ dtw2, const float* __restrict__ dtb2,
    float* __restrict__ y_px){
  __shared__ float ystage[2][2][LL + HH];   // [chain-in-blk][n-half][pad l]
  int wv   = threadIdx.x >> 6;
  int lane = threadIdx.x & 63;
  int c    = wv >> 1;                       // chain in block
  int nh   = wv & 1;                        // n-half
  int chain = blockIdx.x * 2 + c;           // = (mb*KK + k)*DIN + d
  int d   = chain % DIN;
  int mbk = chain / DIN;
  int k   = mbk % KK;
  int mb  = mbk / KK;
  int m = mb / BN, b = mb % BN;
  int kd = k * DIN + d;
  bool rev = (k >= 2);

  const float* Alog = (m == 0 ? Alog1 : Alog2) + kd * NS + nh * 8;
  float An[8];
  #pragma unroll
  for (int n = 0; n < 8; ++n) An[n] = -__expf(Alog[n]);
  float Dv = (m == 0 ? D2 : D1)[kd];
  const float* dtw = (m == 0 ? dtw1 : dtw2) + kd * RR;
  float w0 = dtw[0], w1 = dtw[1], w2 = dtw[2], w3 = dtw[3], w4 = dtw[4], w5 = dtw[5];
  float dbias = (m == 0 ? dtb1 : dtb2)[kd];

  const float* t0 = tdt_all + (size_t)mbk * RR * LL;    // [r][q] rows
  const float* Bp = B_ch + (size_t)mbk * LL * NS + nh * 8;
  int mbk_o = ((1 - m) * BN + b) * KK + k;              // other modality's C
  const float* Cp = C_ch + (size_t)mbk_o * LL * NS + nh * 8;
  const float* urow = ((k & 1) ? u_chT : u_chA) + ((size_t)mb * DIN + d) * LL;

  float h[8], aP[8];
  #pragma unroll
  for (int n = 0; n < 8; ++n){ h[n] = 0.f; aP[n] = 1.f; }

  // phase 1: local chunk scan -> (prod dA, h_local_end)
  for (int s = 0; s < CH; ++s){
    int q = s * 64 + lane;
    float dtpre = w0 * t0[q] + w1 * t0[LL + q] + w2 * t0[2 * LL + q]
                + w3 * t0[3 * LL + q] + w4 * t0[4 * LL + q] + w5 * t0[5 * LL + q] + dbias;
    float dt = softplusf_(dtpre);
    float u  = urow[rev ? (LL - 1 - q) : q];
    float du = dt * u;
    const float4* B4 = reinterpret_cast<const float4*>(Bp + (size_t)q * NS);
    float4 b0 = B4[0], b1 = B4[1];
    float Bv[8] = {b0.x, b0.y, b0.z, b0.w, b1.x, b1.y, b1.z, b1.w};
    #pragma unroll
    for (int n = 0; n < 8; ++n){
      float dA = __expf(dt * An[n]);
      aP[n] *= dA;
      h[n] = dA * h[n] + du * Bv[n];
    }
  }
  // Kogge-Stone inclusive scan of (aP,h) across 64 lanes (chunk order)
  #pragma unroll
  for (int off = 1; off < 64; off <<= 1){
    #pragma unroll
    for (int n = 0; n < 8; ++n){
      float ap = __shfl_up(aP[n], off);
      float bp = __shfl_up(h[n],  off);
      if (lane >= off){
        h[n]  = aP[n] * bp + h[n];
        aP[n] = aP[n] * ap;
      }
    }
  }
  // carry-in for this chunk = inclusive result of previous lane
  #pragma unroll
  for (int n = 0; n < 8; ++n){
    float v = __shfl_up(h[n], 1);
    h[n] = (lane == 0) ? 0.f : v;
  }
  // phase 2: rescan with carry, emit partial y into LDS
  for (int s = 0; s < CH; ++s){
    int q = s * 64 + lane;
    float dtpre = w0 * t0[q] + w1 * t0[LL + q] + w2 * t0[2 * LL + q]
                + w3 * t0[3 * LL + q] + w4 * t0[4 * LL + q] + w5 * t0[5 * LL + q] + dbias;
    float dt = softplusf_(dtpre);
    float u  = urow[rev ? (LL - 1 - q) : q];
    float du = dt * u;
    const float4* B4 = reinterpret_cast<const float4*>(Bp + (size_t)q * NS);
    float4 b0 = B4[0], b1 = B4[1];
    float Bv[8] = {b0.x, b0.y, b0.z, b0.w, b1.x, b1.y, b1.z, b1.w};
    const float4* C4 = reinterpret_cast<const float4*>(Cp + (size_t)q * NS);
    float4 c0 = C4[0], c1 = C4[1];
    float Cv[8] = {c0.x, c0.y, c0.z, c0.w, c1.x, c1.y, c1.z, c1.w};
    float y = 0.f;
    #pragma unroll
    for (int n = 0; n < 8; ++n){
      float dA = __expf(dt * An[n]);
      h[n] = dA * h[n] + du * Bv[n];
      y += h[n] * Cv[n];
    }
    if (nh == 0) y += Dv * u;
    int l = lane * CH + s;
    ystage[c][nh][l + l / WW] = y;
  }
  __syncthreads();
  // flush in PIXEL order (sum the two n-half partials); fold reversal and
  // transpose here. both chains of this block share the same k.
  for (int idx = threadIdx.x; idx < 2 * LL; idx += 256){
    int cc = idx / LL, qq = idx - cc * LL;
    int l;
    if      (k == 0) l = qq;
    else if (k == 1) l = (qq % WW) * WW + qq / WW;
    else if (k == 2) l = LL - 1 - qq;
    else             { int qt = (qq % WW) * WW + qq / WW; l = LL - 1 - qt; }
    int li = l + l / WW;
    y_px[(size_t)(blockIdx.x * 2 + cc) * LL + qq] = ystage[cc][0][li] + ystage[cc][1][li];
  }
}

// ------ K5: merge (4 coalesced adds) + LayerNorm + fused cross SE -------
// grid: (L/32, 2*B), block 256. y_final layout [mb][p][d]
__global__ void k_merge(const float* __restrict__ y_px, const float* __restrict__ sq,
                        const float* __restrict__ fc1_w1, const float* __restrict__ fc1_w2,
                        const float* __restrict__ fc2_w1, const float* __restrict__ fc2_w2,
                        const float* __restrict__ n1g, const float* __restrict__ n1b,
                        const float* __restrict__ n2g, const float* __restrict__ n2b,
                        float* __restrict__ y_final){
  __shared__ float acc[DIN][33];
  __shared__ float ps[8][32], ps2[8][32];
  __shared__ float mu_s[32], inv_s[32];
  __shared__ float sqs[DIN], hid[12], exc_s[DIN];
  int p0 = blockIdx.x * 32;
  int mb = blockIdx.y; int m = mb / BN, b = mb % BN;
  const float* yb = y_px + (size_t)mb * KK * DIN * LL;
  for (int idx = threadIdx.x; idx < DIN * 32; idx += 256){
    int dd = idx >> 5, pp = idx & 31;
    size_t o = (size_t)dd * LL + p0 + pp;
    acc[dd][pp] = yb[o] + yb[(size_t)DIN * LL + o]
                + yb[2 * (size_t)DIN * LL + o] + yb[3 * (size_t)DIN * LL + o];
  }
  // cross SE: y_m is scaled by exc of modality (1-m)
  int mbo = (1 - m) * BN + b;
  const float* w1 = (m == 1 ? fc1_w1 : fc2_w1);
  const float* w2 = (m == 1 ? fc1_w2 : fc2_w2);
  if (threadIdx.x < DIN) sqs[threadIdx.x] = sq[mbo * DIN + threadIdx.x];
  __syncthreads();
  if (threadIdx.x < 12){
    float a = 0.f;
    for (int cch = 0; cch < DIN; ++cch) a += w1[threadIdx.x * DIN + cch] * sqs[cch];
    hid[threadIdx.x] = a * sigmoidf_(a);
  }
  {
    int pp = threadIdx.x & 31, qr = threadIdx.x >> 5;
    float s = 0.f, s2 = 0.f;
    #pragma unroll 4
    for (int j = 0; j < 24; ++j){ float v = acc[qr * 24 + j][pp]; s += v; s2 += v * v; }
    ps[qr][pp] = s; ps2[qr][pp] = s2;
  }
  __syncthreads();
  if (threadIdx.x < 32){
    int pp = threadIdx.x;
    float s = 0.f, s2 = 0.f;
    #pragma unroll
    for (int qr = 0; qr < 8; ++qr){ s += ps[qr][pp]; s2 += ps2[qr][pp]; }
    float mu  = s * (1.0f / DIN);
    float var = s2 * (1.0f / DIN) - mu * mu;
    mu_s[pp] = mu; inv_s[pp] = rsqrtf(var + 1e-5f);
  }
  if (threadIdx.x >= 64 && threadIdx.x < 64 + DIN){
    int dd = threadIdx.x - 64;
    float e = 0.f;
    #pragma unroll
    for (int j = 0; j < 12; ++j) e += w2[dd * 12 + j] * hid[j];
    exc_s[dd] = sigmoidf_(e);
  }
  __syncthreads();
  const float* g  = (m == 0 ? n1g : n2g);
  const float* bb = (m == 0 ? n1b : n2b);
  for (int idx = threadIdx.x; idx < DIN * 32; idx += 256){
    int pp = idx / DIN, dd = idx - pp * DIN;
    float v = (acc[dd][pp] - mu_s[pp]) * inv_s[pp] * g[dd] + bb[dd];
    v *= exc_s[dd];
    y_final[((size_t)mb * LL + p0 + pp) * DIN + dd] = v;
  }
}

// ---------------- K6: out_proj (96 x 384) ----------------
// grid: (L/16, B), block 256. float4 chunks, reg-blocked 6 outputs
__global__ void k_out(const float* __restrict__ y_final, const float* __restrict__ wout,
                      float* __restrict__ out){
  __shared__ float yt[16][388];
  int p0 = blockIdx.x * 16;
  int b  = blockIdx.y;
  for (int idx = threadIdx.x; idx < 16 * 384; idx += 256){
    int pp = idx / 384, cch = idx % 384;
    int m = cch / DIN, dd = cch % DIN;
    yt[pp][cch] = y_final[(((size_t)(m * BN + b)) * LL + p0 + pp) * DIN + dd];
  }
  __syncthreads();
  int pp = threadIdx.x & 15;
  int o0 = (threadIdx.x >> 4) * 6;       // 16 groups x 6 outputs
  float acc[6];
  #pragma unroll
  for (int i = 0; i < 6; ++i) acc[i] = 0.f;
  const float4* yv = reinterpret_cast<const float4*>(yt[pp]);
  for (int cc = 0; cc < 96; ++cc){
    float4 x4 = yv[cc];
    #pragma unroll
    for (int i = 0; i < 6; ++i){
      float4 w4 = *reinterpret_cast<const float4*>(wout + (o0 + i) * 2 * DIN + cc * 4);
      acc[i] += w4.x * x4.x + w4.y * x4.y + w4.z * x4.z + w4.w * x4.w;
    }
  }
  #pragma unroll
  for (int i = 0; i < 6; ++i)
    out[((size_t)b * CIN + o0 + i) * LL + p0 + pp] = acc[i];
}

extern "C" void kernel_launch(void* const* d_in, const int* in_sizes, int n_in,
                              void* d_out, int out_size, void* d_ws, size_t ws_size,
                              hipStream_t stream){
  const float* x_rgb   = (const float*)d_in[0];
  const float* x_e     = (const float*)d_in[1];
  const float* in_w    = (const float*)d_in[2];
  const float* in_mx_w = (const float*)d_in[3];
  const float* conv_w  = (const float*)d_in[4];
  const float* conv_b  = (const float*)d_in[5];
  const float* xp1     = (const float*)d_in[6];
  const float* xp2     = (const float*)d_in[7];
  const float* dtw1    = (const float*)d_in[8];
  const float* dtb1    = (const float*)d_in[9];
  const float* dtw2    = (const float*)d_in[10];
  const float* dtb2    = (const float*)d_in[11];
  const float* Alog1   = (const float*)d_in[12];
  const float* Alog2   = (const float*)d_in[13];
  const float* D1      = (const float*)d_in[14];
  const float* D2      = (const float*)d_in[15];
  const float* n1g     = (const float*)d_in[16];
  const float* n1b     = (const float*)d_in[17];
  const float* n2g     = (const float*)d_in[18];
  const float* n2b     = (const float*)d_in[19];
  const float* fc1_w1  = (const float*)d_in[20];
  const float* fc1_w2  = (const float*)d_in[21];
  const float* fc2_w1  = (const float*)d_in[22];
  const float* fc2_w2  = (const float*)d_in[23];
  const float* wout    = (const float*)d_in[24];

  float* ws = (float*)d_ws;
  // region plan (floats), total 12,032,768 (= 48.1 MB):
  //   [0,        1228800) u_chA   (k_conv -> k_scan)
  //   [1228800,  2457600) u_chT   (k_conv -> k_scan)
  //   [2457600,  3686400) x_act   (k_conv -> k_xproj); y_final aliases after
  //   [3686400,  4915200) x_actT  (k_conv -> k_xproj)
  //   [4915200,  6144000) xproj   (k_inproj -> k_conv)
  //   [6144000, 11059200) y_px    (k_scan -> k_merge)
  //   [11059200,11468800) B_ch
  //   [11468800,11878400) C_ch
  //   [11878400,12032000) tdt_ch  [mbk][r][q]
  //   [12032000,12032768) sq
  float* u_chA   = ws;
  float* u_chT   = ws + 1228800;
  float* x_act   = ws + 2457600;
  float* x_actT  = ws + 3686400;
  float* xproj   = ws + 4915200;
  float* y_final = ws + 2457600;      // alias: x_act dead after k_xproj
  float* y_px    = ws + 6144000;
  float* B_ch    = ws + 11059200;
  float* C_ch    = ws + 11468800;
  float* tdt_ch  = ws + 11878400;
  float* sq      = ws + 12032000;

  k_inproj<<<dim3(LL / 16, 2 * BN), 256, 0, stream>>>(x_rgb, x_e, in_w, in_mx_w, xproj);
  k_conv  <<<dim3(DIN, 2 * BN), 256, 0, stream>>>(xproj, conv_w, conv_b,
                                                  x_act, x_actT, u_chA, u_chT, sq);
  k_xproj <<<dim3(LL / 64, KK, 2 * BN), 256, 0, stream>>>(x_act, x_actT, xp1, xp2,
                                                          tdt_ch, B_ch, C_ch);
  k_scan  <<<1536, 256, 0, stream>>>(u_chA, u_chT, tdt_ch, B_ch, C_ch,
                                     Alog1, Alog2, D1, D2,
                                     dtw1, dtb1, dtw2, dtb2, y_px);
  k_merge <<<dim3(LL / 32, 2 * BN), 256, 0, stream>>>(y_px, sq,
                                                      fc1_w1, fc1_w2, fc2_w1, fc2_w2,
                                                      n1g, n1b, n2g, n2b, y_final);
  k_out   <<<dim3(LL / 16, BN), 256, 0, stream>>>(y_final, wout, (float*)d_out);
}